// Round 11
// baseline (765.413 us; speedup 1.0000x reference)
//
#include <hip/hip_runtime.h>

typedef float f32x4 __attribute__((ext_vector_type(4)));
typedef __bf16 bf16x8 __attribute__((ext_vector_type(8)));
typedef unsigned short u16x8 __attribute__((ext_vector_type(8)));
typedef unsigned int u32x4 __attribute__((ext_vector_type(4)));

#define NBH 16
#define NSEQ 4096
#define DH 64

__device__ __forceinline__ unsigned int cvtpk(float lo, float hi) {
  unsigned int r;
  asm("v_cvt_pk_bf16_f32 %0, %1, %2" : "=v"(r) : "v"(lo), "v"(hi));
  return r;
}
__device__ __forceinline__ bf16x8 pk8(const float* f) {
  union { unsigned int u[4]; bf16x8 b; } x;
#pragma unroll
  for (int i = 0; i < 4; ++i) x.u[i] = cvtpk(f[2 * i], f[2 * i + 1]);
  return x.b;
}
__device__ __forceinline__ float bf2f(unsigned short h) {
  return __uint_as_float(((unsigned int)h) << 16);
}
__device__ __forceinline__ void lbar() {
  __builtin_amdgcn_sched_barrier(0);
  asm volatile("s_waitcnt lgkmcnt(0)" ::: "memory");
  __builtin_amdgcn_s_barrier();
  __builtin_amdgcn_sched_barrier(0);
}
__device__ __forceinline__ void ntst4(float* p, f32x4 v) {
  __builtin_nontemporal_store(v, (f32x4*)p);
}

// Fused causal SDPA. Block = complementary 64-row q-tiles {qa=qt, qb=63-qt};
// waves 0-3 tile A, waves 4-7 tile B. Pass 1: 128-wide K-tiles (half the
// barrier/staging events), LDS union overlay. Pass 2: R4-proven protocol
// (K+V double-buffered, 1 lbar/iter, immediate PV); attn stored as 4x
// dwordx4 nontemporal via wave-private Pl readback. out/fill stores nt.
__global__ __launch_bounds__(512, 4) void sdpa_fused(
    const float* __restrict__ qg, const float* __restrict__ kg,
    const float* __restrict__ vg, float* __restrict__ outg) {
  const int bid = blockIdx.x;
  const int xcd = bid & 7;
  const int ii = bid >> 3;       // 0..63
  const int hh = ii >> 5;        // head within XCD
  const int qt = ii & 31;
  const int b = 2 * xcd + hh;    // 2 heads per XCD
  const int qa = qt, qb = 63 - qt;

  const int tid = threadIdx.x;
  const int w = tid >> 6, lane = tid & 63;
  const int g = lane >> 4, c = lane & 15;
  const int grp = w >> 2;                 // 0: tile A, 1: tile B
  const int wr0 = 16 * (w & 3);
  const int qrw = (grp ? qb : qa) * 64;   // wave's q-tile row base
  const int kmax = grp ? qb : qa;         // last 64-wide K-tile (pass 2)
  const int kmax2 = kmax >> 1;            // last 128-wide K-tile (pass 1)
  const int pOff = 16 * w;                // wave-private Pl rows

  const float* qbp = qg + (size_t)b * NSEQ * DH;
  const float* kbp = kg + (size_t)b * NSEQ * DH;
  const float* vbp = vg + (size_t)b * NSEQ * DH;
  float* outb = outg + (size_t)b * NSEQ * DH;
  float* attnb = outg + (size_t)NBH * NSEQ * DH + (size_t)b * NSEQ * NSEQ;

  __shared__ union {
    unsigned short K2[2][128][72];        // pass 1 (36.9 KB)
    struct {                               // pass 2 (55.8 KB)
      unsigned short Kl[2][64][72];
      unsigned int Vt[2][64][37];          // u32 = {bf16 V[2p][d], V[2p+1][d]}
      unsigned short Pl[128][72];          // wave-private 16-row slabs
    } m;
  } sm;

  // ---- Q fragments: row = qrw+wr0+c, k = 32ks+8g+e ----
  bf16x8 aq[2];
  {
    const float* qrow = qbp + (size_t)(qrw + wr0 + c) * DH;
#pragma unroll
    for (int ks = 0; ks < 2; ++ks) {
      float f[8];
      *(float4*)f = *(const float4*)(qrow + 32 * ks + 8 * g);
      *(float4*)(f + 4) = *(const float4*)(qrow + 32 * ks + 8 * g + 4);
      aq[ks] = pk8(f);
    }
  }

  float rinv[4];

  // ================= pass 1: l = sum(exp(s)), 128-wide K =================
  {
    const int r0 = tid >> 2, ch = tid & 3;   // row, 16-float chunk
    float kf2[16];
    auto loadK2 = [&](int s2) {
      const float* s = kbp + (size_t)(s2 * 128 + r0) * DH + ch * 16;
#pragma unroll
      for (int i = 0; i < 4; ++i) *(float4*)(kf2 + 4 * i) = ((const float4*)s)[i];
    };
    auto writeK2 = [&](int cur) {
      unsigned int* dst = (unsigned int*)&sm.K2[cur][r0][ch * 16];
#pragma unroll
      for (int i = 0; i < 8; ++i) dst[i] = cvtpk(kf2[2 * i], kf2[2 * i + 1]);
    };

    const int nst1 = (qb >> 1) + 1;
    float part[4] = {0.f, 0.f, 0.f, 0.f};
    loadK2(0);
    for (int s2 = 0; s2 < nst1; ++s2) {
      const int cur = s2 & 1;
      writeK2(cur);
      lbar();
      if (s2 + 1 < nst1) loadK2(s2 + 1);
      if (s2 <= kmax2) {
#pragma unroll
        for (int cg = 0; cg < 2; ++cg) {
          f32x4 acc[4];
#pragma unroll
          for (int cc = 0; cc < 4; ++cc) acc[cc] = (f32x4){0.f, 0.f, 0.f, 0.f};
#pragma unroll
          for (int ks = 0; ks < 2; ++ks)
#pragma unroll
            for (int cc = 0; cc < 4; ++cc) {
              u16x8 u = *(const u16x8*)&sm.K2[cur][16 * (4 * cg + cc) + c][32 * ks + 8 * g];
              acc[cc] = __builtin_amdgcn_mfma_f32_16x16x32_bf16(aq[ks], __builtin_bit_cast(bf16x8, u), acc[cc], 0, 0, 0);
            }
#pragma unroll
          for (int cc = 0; cc < 4; ++cc)
#pragma unroll
            for (int r = 0; r < 4; ++r) {
              const int j = s2 * 128 + 16 * (4 * cg + cc) + c;
              const int i = qrw + wr0 + 4 * g + r;
              part[r] += (j <= i) ? __expf(acc[cc][r] * 0.125f) : 0.f;
            }
        }
      }
    }
#pragma unroll
    for (int r = 0; r < 4; ++r) {
      float s = part[r];
      s += __shfl_xor(s, 1); s += __shfl_xor(s, 2);
      s += __shfl_xor(s, 4); s += __shfl_xor(s, 8);
      rinv[r] = 1.f / s;
    }
  }

  __syncthreads();  // pass-1 K2 reads done; pass-2 buffers safe to write

  // ================= pass 2: attn + PV (R4 protocol) =================
  {
    const int kj = tid >> 3, kcs = tid & 7;   // K: row kj, 8-float chunk
    const int vp = tid >> 4, dch = tid & 15;  // V: row-pair vp, 4-dim chunk
    float kf[8], vf0[4], vf1[4];

    auto loadK = [&](int kt) {
      const float* s = kbp + (size_t)(kt * 64 + kj) * DH + kcs * 8;
      *(float4*)kf = ((const float4*)s)[0];
      *(float4*)(kf + 4) = ((const float4*)s)[1];
    };
    auto writeK = [&](int cur) {
      u32x4 u;
#pragma unroll
      for (int i = 0; i < 4; ++i) u[i] = cvtpk(kf[2 * i], kf[2 * i + 1]);
      *(u32x4*)&sm.m.Kl[cur][kj][kcs * 8] = u;
    };
    auto loadV = [&](int kt) {
      const float* s0 = vbp + (size_t)(kt * 64 + 2 * vp) * DH + dch * 4;
      *(float4*)vf0 = *(const float4*)s0;
      *(float4*)vf1 = *(const float4*)(s0 + DH);
    };
    auto writeV = [&](int cur) {
#pragma unroll
      for (int e = 0; e < 4; ++e) sm.m.Vt[cur][4 * dch + e][vp] = cvtpk(vf0[e], vf1[e]);
    };

    loadK(0);
    loadV(0);
    f32x4 oacc[4];
#pragma unroll
    for (int ct = 0; ct < 4; ++ct) oacc[ct] = (f32x4){0.f, 0.f, 0.f, 0.f};

    for (int kt = 0; kt <= qb; ++kt) {
      const int cur = kt & 1;
      writeK(cur);
      writeV(cur);
      lbar();
      if (kt < qb) { loadK(kt + 1); loadV(kt + 1); }

      if (kt <= kmax) {
        f32x4 acc[4];
#pragma unroll
        for (int ct = 0; ct < 4; ++ct) acc[ct] = (f32x4){0.f, 0.f, 0.f, 0.f};
#pragma unroll
        for (int ks = 0; ks < 2; ++ks)
#pragma unroll
          for (int ct = 0; ct < 4; ++ct) {
            u16x8 u = *(const u16x8*)&sm.m.Kl[cur][16 * ct + c][32 * ks + 8 * g];
            acc[ct] = __builtin_amdgcn_mfma_f32_16x16x32_bf16(aq[ks], __builtin_bit_cast(bf16x8, u), acc[ct], 0, 0, 0);
          }

#pragma unroll
        for (int ct = 0; ct < 4; ++ct)
#pragma unroll
          for (int r = 0; r < 4; ++r) {
            const int jl = 16 * ct + c;
            const int i = qrw + wr0 + 4 * g + r;
            const int j = kt * 64 + jl;
            const float p = (j <= i) ? __expf(acc[ct][r] * 0.125f) * rinv[r] : 0.f;
            sm.m.Pl[pOff + 4 * g + r][jl] = (unsigned short)cvtpk(p, p);
          }

        // attn store: wave-private readback, 4x dwordx4 nt per lane
        {
          const int lr = lane >> 2, lc = lane & 3;
          u16x8 u0 = *(const u16x8*)&sm.m.Pl[pOff + lr][lc * 16];
          u16x8 u1 = *(const u16x8*)&sm.m.Pl[pOff + lr][lc * 16 + 8];
          float* dst = attnb + (size_t)(qrw + wr0 + lr) * NSEQ + kt * 64 + lc * 16;
          f32x4 f0, f1, f2, f3;
          f0[0] = bf2f(u0[0]); f0[1] = bf2f(u0[1]); f0[2] = bf2f(u0[2]); f0[3] = bf2f(u0[3]);
          f1[0] = bf2f(u0[4]); f1[1] = bf2f(u0[5]); f1[2] = bf2f(u0[6]); f1[3] = bf2f(u0[7]);
          f2[0] = bf2f(u1[0]); f2[1] = bf2f(u1[1]); f2[2] = bf2f(u1[2]); f2[3] = bf2f(u1[3]);
          f3[0] = bf2f(u1[4]); f3[1] = bf2f(u1[5]); f3[2] = bf2f(u1[6]); f3[3] = bf2f(u1[7]);
          ntst4(dst, f0); ntst4(dst + 4, f1); ntst4(dst + 8, f2); ntst4(dst + 12, f3);
        }

        // immediate PV from wave-private Pl + Vt[cur]
        bf16x8 ap[2];
#pragma unroll
        for (int ks = 0; ks < 2; ++ks)
          ap[ks] = __builtin_bit_cast(bf16x8, *(const u16x8*)&sm.m.Pl[pOff + c][32 * ks + 8 * g]);
#pragma unroll
        for (int ks = 0; ks < 2; ++ks)
#pragma unroll
          for (int ct = 0; ct < 4; ++ct) {
            u16x8 bv = *(const u16x8*)&sm.m.Vt[cur][16 * ct + c][16 * ks + 4 * g];
            oacc[ct] = __builtin_amdgcn_mfma_f32_16x16x32_bf16(ap[ks], __builtin_bit_cast(bf16x8, bv), oacc[ct], 0, 0, 0);
          }
      }
    }

    // ---- out write (nt) ----
#pragma unroll
    for (int ct = 0; ct < 4; ++ct)
#pragma unroll
      for (int r = 0; r < 4; ++r) {
        const int i = qrw + wr0 + 4 * g + r;
        __builtin_nontemporal_store(oacc[ct][r], &outb[(size_t)i * DH + 16 * ct + c]);
      }
  }

  // ---- zero-fill strict upper triangles of both tiles (nt) ----
  const f32x4 z = {0.f, 0.f, 0.f, 0.f};
#pragma unroll
  for (int t = 0; t < 2; ++t) {
    const int q0 = t ? qb : qa;
    const int zc0 = 64 * (q0 + 1);
    if (zc0 < NSEQ) {
      const int zw4 = (NSEQ - zc0) >> 2;
      for (int r = 0; r < 64; ++r) {
        float* dst = attnb + (size_t)(q0 * 64 + r) * NSEQ + zc0;
        for (int c4 = tid; c4 < zw4; c4 += 512) ntst4(dst + 4 * c4, z);
      }
    }
  }
}

extern "C" void kernel_launch(void* const* d_in, const int* in_sizes, int n_in,
                              void* d_out, int out_size, void* d_ws, size_t ws_size,
                              hipStream_t stream) {
  (void)in_sizes; (void)n_in; (void)out_size; (void)d_ws; (void)ws_size;
  const float* q = (const float*)d_in[0];
  const float* k = (const float*)d_in[1];
  const float* v = (const float*)d_in[2];
  float* out = (float*)d_out;
  sdpa_fused<<<dim3(512), dim3(512), 0, stream>>>(q, k, v, out);
}

// Round 12
// 421.820 us; speedup vs baseline: 1.8146x; 1.8146x over previous
//
#include <hip/hip_runtime.h>

typedef float f32x4 __attribute__((ext_vector_type(4)));
typedef __bf16 bf16x8 __attribute__((ext_vector_type(8)));
typedef unsigned short u16x8 __attribute__((ext_vector_type(8)));
typedef unsigned int u32x4 __attribute__((ext_vector_type(4)));

#define NBH 16
#define NSEQ 4096
#define DH 64

__device__ __forceinline__ unsigned int cvtpk(float lo, float hi) {
  unsigned int r;
  asm("v_cvt_pk_bf16_f32 %0, %1, %2" : "=v"(r) : "v"(lo), "v"(hi));
  return r;
}
__device__ __forceinline__ bf16x8 pk8(const float* f) {
  union { unsigned int u[4]; bf16x8 b; } x;
#pragma unroll
  for (int i = 0; i < 4; ++i) x.u[i] = cvtpk(f[2 * i], f[2 * i + 1]);
  return x.b;
}
__device__ __forceinline__ float bf2f(unsigned short h) {
  return __uint_as_float(((unsigned int)h) << 16);
}
__device__ __forceinline__ void lbar() {
  __builtin_amdgcn_sched_barrier(0);
  asm volatile("s_waitcnt lgkmcnt(0)" ::: "memory");
  __builtin_amdgcn_s_barrier();
  __builtin_amdgcn_sched_barrier(0);
}

// Fused causal SDPA. Block = complementary 64-row q-tiles {qa=qt, qb=63-qt};
// waves 0-3 tile A, waves 4-7 tile B. Pass 1: 128-wide K-tiles (half the
// barrier/staging events), LDS union overlay. Pass 2: R4-proven protocol
// (K+V double-buffered, 1 lbar/iter, immediate PV); attn stored as 4x
// dwordx4 (plain stores — nt measured 2.4x slower on gfx950, R11).
__global__ __launch_bounds__(512, 4) void sdpa_fused(
    const float* __restrict__ qg, const float* __restrict__ kg,
    const float* __restrict__ vg, float* __restrict__ outg) {
  const int bid = blockIdx.x;
  const int xcd = bid & 7;
  const int ii = bid >> 3;       // 0..63
  const int hh = ii >> 5;        // head within XCD
  const int qt = ii & 31;
  const int b = 2 * xcd + hh;    // 2 heads per XCD
  const int qa = qt, qb = 63 - qt;

  const int tid = threadIdx.x;
  const int w = tid >> 6, lane = tid & 63;
  const int g = lane >> 4, c = lane & 15;
  const int grp = w >> 2;                 // 0: tile A, 1: tile B
  const int wr0 = 16 * (w & 3);
  const int qrw = (grp ? qb : qa) * 64;   // wave's q-tile row base
  const int kmax = grp ? qb : qa;         // last 64-wide K-tile (pass 2)
  const int kmax2 = kmax >> 1;            // last 128-wide K-tile (pass 1)
  const int pOff = 16 * w;                // wave-private Pl rows

  const float* qbp = qg + (size_t)b * NSEQ * DH;
  const float* kbp = kg + (size_t)b * NSEQ * DH;
  const float* vbp = vg + (size_t)b * NSEQ * DH;
  float* outb = outg + (size_t)b * NSEQ * DH;
  float* attnb = outg + (size_t)NBH * NSEQ * DH + (size_t)b * NSEQ * NSEQ;

  __shared__ union {
    unsigned short K2[2][128][72];        // pass 1 (36.9 KB)
    struct {                               // pass 2 (55.8 KB)
      unsigned short Kl[2][64][72];
      unsigned int Vt[2][64][37];          // u32 = {bf16 V[2p][d], V[2p+1][d]}
      unsigned short Pl[128][72];          // wave-private 16-row slabs
    } m;
  } sm;

  // ---- Q fragments: row = qrw+wr0+c, k = 32ks+8g+e ----
  bf16x8 aq[2];
  {
    const float* qrow = qbp + (size_t)(qrw + wr0 + c) * DH;
#pragma unroll
    for (int ks = 0; ks < 2; ++ks) {
      float f[8];
      *(float4*)f = *(const float4*)(qrow + 32 * ks + 8 * g);
      *(float4*)(f + 4) = *(const float4*)(qrow + 32 * ks + 8 * g + 4);
      aq[ks] = pk8(f);
    }
  }

  float rinv[4];

  // ================= pass 1: l = sum(exp(s)), 128-wide K =================
  {
    const int r0 = tid >> 2, ch = tid & 3;   // row, 16-float chunk
    float kf2[16];
    auto loadK2 = [&](int s2) {
      const float* s = kbp + (size_t)(s2 * 128 + r0) * DH + ch * 16;
#pragma unroll
      for (int i = 0; i < 4; ++i) *(float4*)(kf2 + 4 * i) = ((const float4*)s)[i];
    };
    auto writeK2 = [&](int cur) {
      unsigned int* dst = (unsigned int*)&sm.K2[cur][r0][ch * 16];
#pragma unroll
      for (int i = 0; i < 8; ++i) dst[i] = cvtpk(kf2[2 * i], kf2[2 * i + 1]);
    };

    const int nst1 = (qb >> 1) + 1;
    float part[4] = {0.f, 0.f, 0.f, 0.f};
    loadK2(0);
    for (int s2 = 0; s2 < nst1; ++s2) {
      const int cur = s2 & 1;
      writeK2(cur);
      lbar();
      if (s2 + 1 < nst1) loadK2(s2 + 1);
      if (s2 <= kmax2) {
#pragma unroll
        for (int cg = 0; cg < 2; ++cg) {
          f32x4 acc[4];
#pragma unroll
          for (int cc = 0; cc < 4; ++cc) acc[cc] = (f32x4){0.f, 0.f, 0.f, 0.f};
#pragma unroll
          for (int ks = 0; ks < 2; ++ks)
#pragma unroll
            for (int cc = 0; cc < 4; ++cc) {
              u16x8 u = *(const u16x8*)&sm.K2[cur][16 * (4 * cg + cc) + c][32 * ks + 8 * g];
              acc[cc] = __builtin_amdgcn_mfma_f32_16x16x32_bf16(aq[ks], __builtin_bit_cast(bf16x8, u), acc[cc], 0, 0, 0);
            }
#pragma unroll
          for (int cc = 0; cc < 4; ++cc)
#pragma unroll
            for (int r = 0; r < 4; ++r) {
              const int j = s2 * 128 + 16 * (4 * cg + cc) + c;
              const int i = qrw + wr0 + 4 * g + r;
              part[r] += (j <= i) ? __expf(acc[cc][r] * 0.125f) : 0.f;
            }
        }
      }
    }
#pragma unroll
    for (int r = 0; r < 4; ++r) {
      float s = part[r];
      s += __shfl_xor(s, 1); s += __shfl_xor(s, 2);
      s += __shfl_xor(s, 4); s += __shfl_xor(s, 8);
      rinv[r] = 1.f / s;
    }
  }

  __syncthreads();  // pass-1 K2 reads done; pass-2 buffers safe to write

  // ================= pass 2: attn + PV (R4 protocol) =================
  {
    const int kj = tid >> 3, kcs = tid & 7;   // K: row kj, 8-float chunk
    const int vp = tid >> 4, dch = tid & 15;  // V: row-pair vp, 4-dim chunk
    float kf[8], vf0[4], vf1[4];

    auto loadK = [&](int kt) {
      const float* s = kbp + (size_t)(kt * 64 + kj) * DH + kcs * 8;
      *(float4*)kf = ((const float4*)s)[0];
      *(float4*)(kf + 4) = ((const float4*)s)[1];
    };
    auto writeK = [&](int cur) {
      u32x4 u;
#pragma unroll
      for (int i = 0; i < 4; ++i) u[i] = cvtpk(kf[2 * i], kf[2 * i + 1]);
      *(u32x4*)&sm.m.Kl[cur][kj][kcs * 8] = u;
    };
    auto loadV = [&](int kt) {
      const float* s0 = vbp + (size_t)(kt * 64 + 2 * vp) * DH + dch * 4;
      *(float4*)vf0 = *(const float4*)s0;
      *(float4*)vf1 = *(const float4*)(s0 + DH);
    };
    auto writeV = [&](int cur) {
#pragma unroll
      for (int e = 0; e < 4; ++e) sm.m.Vt[cur][4 * dch + e][vp] = cvtpk(vf0[e], vf1[e]);
    };

    loadK(0);
    loadV(0);
    f32x4 oacc[4];
#pragma unroll
    for (int ct = 0; ct < 4; ++ct) oacc[ct] = (f32x4){0.f, 0.f, 0.f, 0.f};

    for (int kt = 0; kt <= qb; ++kt) {
      const int cur = kt & 1;
      writeK(cur);
      writeV(cur);
      lbar();
      if (kt < qb) { loadK(kt + 1); loadV(kt + 1); }

      if (kt <= kmax) {
        f32x4 acc[4];
#pragma unroll
        for (int ct = 0; ct < 4; ++ct) acc[ct] = (f32x4){0.f, 0.f, 0.f, 0.f};
#pragma unroll
        for (int ks = 0; ks < 2; ++ks)
#pragma unroll
          for (int ct = 0; ct < 4; ++ct) {
            u16x8 u = *(const u16x8*)&sm.m.Kl[cur][16 * ct + c][32 * ks + 8 * g];
            acc[ct] = __builtin_amdgcn_mfma_f32_16x16x32_bf16(aq[ks], __builtin_bit_cast(bf16x8, u), acc[ct], 0, 0, 0);
          }

#pragma unroll
        for (int ct = 0; ct < 4; ++ct)
#pragma unroll
          for (int r = 0; r < 4; ++r) {
            const int jl = 16 * ct + c;
            const int i = qrw + wr0 + 4 * g + r;
            const int j = kt * 64 + jl;
            const float p = (j <= i) ? __expf(acc[ct][r] * 0.125f) * rinv[r] : 0.f;
            sm.m.Pl[pOff + 4 * g + r][jl] = (unsigned short)cvtpk(p, p);
          }

        // attn store: wave-private readback, 4x dwordx4 per lane
        {
          const int lr = lane >> 2, lc = lane & 3;
          u16x8 u0 = *(const u16x8*)&sm.m.Pl[pOff + lr][lc * 16];
          u16x8 u1 = *(const u16x8*)&sm.m.Pl[pOff + lr][lc * 16 + 8];
          float* dst = attnb + (size_t)(qrw + wr0 + lr) * NSEQ + kt * 64 + lc * 16;
          float4 f0, f1, f2, f3;
          f0.x = bf2f(u0[0]); f0.y = bf2f(u0[1]); f0.z = bf2f(u0[2]); f0.w = bf2f(u0[3]);
          f1.x = bf2f(u0[4]); f1.y = bf2f(u0[5]); f1.z = bf2f(u0[6]); f1.w = bf2f(u0[7]);
          f2.x = bf2f(u1[0]); f2.y = bf2f(u1[1]); f2.z = bf2f(u1[2]); f2.w = bf2f(u1[3]);
          f3.x = bf2f(u1[4]); f3.y = bf2f(u1[5]); f3.z = bf2f(u1[6]); f3.w = bf2f(u1[7]);
          ((float4*)dst)[0] = f0; ((float4*)dst)[1] = f1;
          ((float4*)dst)[2] = f2; ((float4*)dst)[3] = f3;
        }

        // immediate PV from wave-private Pl + Vt[cur]
        bf16x8 ap[2];
#pragma unroll
        for (int ks = 0; ks < 2; ++ks)
          ap[ks] = __builtin_bit_cast(bf16x8, *(const u16x8*)&sm.m.Pl[pOff + c][32 * ks + 8 * g]);
#pragma unroll
        for (int ks = 0; ks < 2; ++ks)
#pragma unroll
          for (int ct = 0; ct < 4; ++ct) {
            u16x8 bv = *(const u16x8*)&sm.m.Vt[cur][16 * ct + c][16 * ks + 4 * g];
            oacc[ct] = __builtin_amdgcn_mfma_f32_16x16x32_bf16(ap[ks], __builtin_bit_cast(bf16x8, bv), oacc[ct], 0, 0, 0);
          }
      }
    }

    // ---- out write ----
#pragma unroll
    for (int ct = 0; ct < 4; ++ct)
#pragma unroll
      for (int r = 0; r < 4; ++r) {
        const int i = qrw + wr0 + 4 * g + r;
        outb[(size_t)i * DH + 16 * ct + c] = oacc[ct][r];
      }
  }

  // ---- zero-fill strict upper triangles of both tiles ----
  const float4 z = {0.f, 0.f, 0.f, 0.f};
#pragma unroll
  for (int t = 0; t < 2; ++t) {
    const int q0 = t ? qb : qa;
    const int zc0 = 64 * (q0 + 1);
    if (zc0 < NSEQ) {
      const int zw4 = (NSEQ - zc0) >> 2;
      for (int r = 0; r < 64; ++r) {
        float4* dst = (float4*)(attnb + (size_t)(q0 * 64 + r) * NSEQ + zc0);
        for (int c4 = tid; c4 < zw4; c4 += 512) dst[c4] = z;
      }
    }
  }
}

extern "C" void kernel_launch(void* const* d_in, const int* in_sizes, int n_in,
                              void* d_out, int out_size, void* d_ws, size_t ws_size,
                              hipStream_t stream) {
  (void)in_sizes; (void)n_in; (void)out_size; (void)d_ws; (void)ws_size;
  const float* q = (const float*)d_in[0];
  const float* k = (const float*)d_in[1];
  const float* v = (const float*)d_in[2];
  float* out = (float*)d_out;
  sdpa_fused<<<dim3(512), dim3(512), 0, stream>>>(q, k, v, out);
}